// Round 8
// baseline (781.217 us; speedup 1.0000x reference)
//
#include <hip/hip_runtime.h>

// ---------------- problem constants ----------------
#define T_TOK 2048
#define NEXP  8
#define H_DIM 1024
#define I_DIM 4096

#define KP13 (H_DIM/8)     // 128
#define N13  (2*I_DIM)     // 8192
#define KP2  (I_DIM/8)     // 512
#define N2   (H_DIM)       // 1024
#define NG13 8
#define NG2  32

#define KSPLIT2 4
#define KLEN2 (I_DIM/KSPLIT2)   // 1024
#define LDSK  1032               // padded col stride (bf16 elems)

typedef __bf16 bf16x8 __attribute__((ext_vector_type(8)));
typedef float  f32x4  __attribute__((ext_vector_type(4)));
typedef int    i32x4  __attribute__((ext_vector_type(4)));

// ---------------- workspace layout (bytes) ----------------
#define WS_COUNTS 0
#define WS_OFFS   64
#define WS_CURS   128
#define WS_TOKE   256
#define WS_TOKW   (WS_TOKE  + 2*T_TOK*4)
#define WS_PLIST  (WS_TOKW  + 2*T_TOK*4)
#define WS_PW     (WS_PLIST + 2*T_TOK*4)
#define PAIR_PAD  (2*T_TOK + 128)
#define WS_XG     131072
#define WS_ACT    (WS_XG + PAIR_PAD*H_DIM*2)   // bf16 act[pairs][I_DIM]

// =====================================================================
// Routing
// =====================================================================
__global__ void k_route(const float* __restrict__ logits,
                        int* __restrict__ counts,
                        int* __restrict__ tok_e, float* __restrict__ tok_w) {
    int t = blockIdx.x * blockDim.x + threadIdx.x;
    if (t >= T_TOK) return;
    float l[NEXP];
    #pragma unroll
    for (int e = 0; e < NEXP; e++) l[e] = logits[t * NEXP + e];
    int i0 = 0; float b0 = l[0];
    #pragma unroll
    for (int e = 1; e < NEXP; e++) if (l[e] > b0) { b0 = l[e]; i0 = e; }
    int i1 = -1; float b1 = -1e30f;
    #pragma unroll
    for (int e = 0; e < NEXP; e++) if (e != i0 && l[e] > b1) { b1 = l[e]; i1 = e; }
    float w1 = 1.f / (1.f + __expf(b0 - b1));
    float w0 = 1.f - w1;
    tok_e[2*t] = i0; tok_e[2*t+1] = i1;
    tok_w[2*t] = w0; tok_w[2*t+1] = w1;
    atomicAdd(&counts[i0], 1);
    atomicAdd(&counts[i1], 1);
}

__global__ void k_scan(const int* __restrict__ counts,
                       int* __restrict__ offs, int* __restrict__ curs) {
    if (threadIdx.x == 0) {
        int s = 0;
        for (int e = 0; e < NEXP; e++) { offs[e] = s; curs[e] = s; s += counts[e]; }
        offs[NEXP] = s;
    }
}

__global__ void k_scatter(const int* __restrict__ tok_e, const float* __restrict__ tok_w,
                          int* __restrict__ curs,
                          int* __restrict__ plist, float* __restrict__ pw) {
    int t = blockIdx.x * blockDim.x + threadIdx.x;
    if (t >= T_TOK) return;
    #pragma unroll
    for (int s = 0; s < 2; s++) {
        int e = tok_e[2*t+s];
        int pos = atomicAdd(&curs[e], 1);
        plist[pos] = t;
        pw[pos] = tok_w[2*t+s];
    }
}

__global__ void k_gather(const float* __restrict__ x, const int* __restrict__ plist,
                         __bf16* __restrict__ xg) {
    int p = blockIdx.x;
    int t = plist[p];
    int i = threadIdx.x;
    const f32x4* src = reinterpret_cast<const f32x4*>(x + (size_t)t * H_DIM);
    f32x4 v0 = src[i*2], v1 = src[i*2+1];
    __align__(16) __bf16 tb[8];
    #pragma unroll
    for (int j = 0; j < 4; j++) { tb[j] = (__bf16)v0[j]; tb[4+j] = (__bf16)v1[j]; }
    *reinterpret_cast<f32x4*>(xg + (size_t)p * H_DIM + i*8) = *reinterpret_cast<f32x4*>(tb);
}

// =====================================================================
// GEMM1 (B-stationary): block owns (e, 64 logical cols), dequants its
// int4 strip ONCE into LDS (full K=1024 resident), then loops all m-tiles
// of the expert with a barrier-free K-loop (A-frags direct from global).
// Logical col r interleaves gate/up in 16-groups: rows 0-7 gate, 8-15 up.
// =====================================================================
__global__ __launch_bounds__(256, 1) void k_gemm1(
    const __bf16* __restrict__ xg,
    const int*    __restrict__ w13q,
    const float*  __restrict__ w13s,
    const int*    __restrict__ g13,
    const int*    __restrict__ offs,
    const float*  __restrict__ pw,
    __bf16*       __restrict__ act) {

    const int e   = blockIdx.x >> 7;
    const int nb  = blockIdx.x & 127;
    const int n0r = nb * 64;
    const int mstart = offs[e], mend = offs[e+1];
    const int mcount = mend - mstart;
    if (mcount <= 0) return;

    __shared__ __align__(16) __bf16 Bs[64 * LDSK];   // 129 KB
    __shared__ float s13t[NG13 * 64];                // 2 KB
    __shared__ float wts[1024];                      // 4 KB

    const int tid = threadIdx.x;
    const int wv = tid >> 6, lane = tid & 63;
    const int lrow = lane & 15, quad = lane >> 4;

    const int c = tid & 63;
    const int r = n0r + c;
    const int S = ((r >> 4) << 3) + (r & 7) + (((r >> 3) & 1) ? I_DIM : 0);

    // scale LUT + routing weights
    for (int i = tid; i < NG13 * 64; i += 256) {
        int g = i >> 6, cc = i & 63;
        int rr2 = n0r + cc;
        int Sc = ((rr2 >> 4) << 3) + (rr2 & 7) + (((rr2 >> 3) & 1) ? I_DIM : 0);
        s13t[i] = w13s[(size_t)e * NG13 * N13 + (size_t)g * N13 + Sc];
    }
    for (int m = tid; m < 1024; m += 256)
        wts[m] = (m < mcount) ? pw[mstart + m] : 0.f;
    __syncthreads();

    // ---- dequant own column strip into LDS (once, zero redundancy) ----
    {
        const int kp0 = tid >> 6;
        const int* qcol = w13q + (size_t)e * KP13 * N13 + S;
        const int* gcol = g13 + e * H_DIM;
        #pragma unroll
        for (int kp = kp0; kp < KP13; kp += 4) {
            int qv = qcol[(size_t)kp * N13];
            const i32x4* gp = reinterpret_cast<const i32x4*>(gcol + kp*8);
            i32x4 ga = gp[0], gb = gp[1];
            int gs[8] = {ga.x, ga.y, ga.z, ga.w, gb.x, gb.y, gb.z, gb.w};
            __align__(16) __bf16 tmp[8];
            #pragma unroll
            for (int j = 0; j < 8; j++)
                tmp[j] = (__bf16)((float)(((qv >> (4*j)) & 15) - 8) * s13t[gs[j]*64 + c]);
            *reinterpret_cast<f32x4*>(&Bs[c * LDSK + kp * 8]) = *reinterpret_cast<f32x4*>(tmp);
        }
    }
    __syncthreads();

    // ---- barrier-free compute over all m-tiles ----
    const __bf16* bp = &Bs[lrow * LDSK + quad * 8];
    const int nmt = (mcount + 127) >> 7;
    for (int mt = 0; mt < nmt; mt++) {
        const __bf16* ap0 = xg + (size_t)(mstart + mt*128 + wv*32 + lrow) * H_DIM + quad*8;
        const __bf16* ap1 = ap0 + (size_t)16 * H_DIM;

        f32x4 acc[2][4];
        #pragma unroll
        for (int i = 0; i < 2; i++)
            #pragma unroll
            for (int j = 0; j < 4; j++) acc[i][j] = (f32x4)(0.f);

        auto loadT = [&](int kt, bf16x8& A0, bf16x8& A1, bf16x8* B) {
            A0 = *reinterpret_cast<const bf16x8*>(ap0 + kt*32);
            A1 = *reinterpret_cast<const bf16x8*>(ap1 + kt*32);
            #pragma unroll
            for (int j = 0; j < 4; j++)
                B[j] = *reinterpret_cast<const bf16x8*>(bp + j*16*LDSK + kt*32);
        };
        auto compT = [&](bf16x8 A0, bf16x8 A1, const bf16x8* B) {
            #pragma unroll
            for (int j = 0; j < 4; j++) {
                acc[0][j] = __builtin_amdgcn_mfma_f32_16x16x32_bf16(A0, B[j], acc[0][j], 0, 0, 0);
                acc[1][j] = __builtin_amdgcn_mfma_f32_16x16x32_bf16(A1, B[j], acc[1][j], 0, 0, 0);
            }
        };

        bf16x8 xa0, xa1, xb[4], ya0, ya1, yb[4];
        loadT(0, xa0, xa1, xb);
        #pragma unroll
        for (int kt = 0; kt < 32; kt += 2) {
            loadT(kt+1, ya0, ya1, yb);
            compT(xa0, xa1, xb);
            if (kt+2 < 32) loadT(kt+2, xa0, xa1, xb);
            compT(ya0, ya1, yb);
        }

        // epilogue: silu(gate)*up * weight; lrow<8 gate, lrow>=8 up partner
        #pragma unroll
        for (int j = 0; j < 4; j++) {
            const int c0 = (n0r + 16*j) >> 1;
            #pragma unroll
            for (int i = 0; i < 2; i++)
                #pragma unroll
                for (int rr = 0; rr < 4; rr++) {
                    float v = acc[i][j][rr];
                    float partner = __shfl_xor(v, 8, 64);
                    int m = mt*128 + wv*32 + i*16 + quad*4 + rr;
                    if (lrow < 8 && m < mcount) {
                        float a = (v / (1.f + __expf(-v))) * partner * wts[m];
                        act[(size_t)(mstart + m) * I_DIM + c0 + lrow] = (__bf16)a;
                    }
                }
        }
    }
}

// =====================================================================
// GEMM2 (B-stationary, split-K): block owns (e, 64 out-cols, K-quarter).
// =====================================================================
__global__ __launch_bounds__(256, 1) void k_gemm2(
    const __bf16* __restrict__ act,
    const int*    __restrict__ w2q,
    const float*  __restrict__ w2s,
    const int*    __restrict__ g2,
    const int*    __restrict__ offs,
    const int*    __restrict__ plist,
    float*        __restrict__ out) {

    const int e  = blockIdx.x >> 6;
    const int ks = (blockIdx.x >> 4) & 3;
    const int nb = blockIdx.x & 15;
    const int n0 = nb * 64;
    const int kz = ks * KLEN2;
    const int mstart = offs[e], mend = offs[e+1];
    const int mcount = mend - mstart;
    if (mcount <= 0) return;

    __shared__ __align__(16) __bf16 Bs[64 * LDSK];   // 129 KB
    __shared__ float s2t[NG2 * 64];                  // 8 KB
    __shared__ int   toks[1024];                     // 4 KB

    const int tid = threadIdx.x;
    const int wv = tid >> 6, lane = tid & 63;
    const int lrow = lane & 15, quad = lane >> 4;
    const int c = tid & 63;

    for (int i = tid; i < NG2 * 64; i += 256) {
        int g = i >> 6, cc = i & 63;
        s2t[i] = w2s[(size_t)e * NG2 * N2 + (size_t)g * N2 + n0 + cc];
    }
    for (int m = tid; m < 1024; m += 256)
        toks[m] = (m < mcount) ? plist[mstart + m] : 0;
    __syncthreads();

    // ---- dequant own W2 strip (cols n0.., k in [kz, kz+1024)) ----
    {
        const int kp0 = tid >> 6;
        const int* qcol = w2q + (size_t)e * KP2 * N2 + (size_t)(kz >> 3) * N2 + n0 + c;
        const int* gcol = g2 + e * I_DIM + kz;
        #pragma unroll
        for (int kp = kp0; kp < 128; kp += 4) {
            int qv = qcol[(size_t)kp * N2];
            const i32x4* gp = reinterpret_cast<const i32x4*>(gcol + kp*8);
            i32x4 ga = gp[0], gb = gp[1];
            int gs[8] = {ga.x, ga.y, ga.z, ga.w, gb.x, gb.y, gb.z, gb.w};
            __align__(16) __bf16 tmp[8];
            #pragma unroll
            for (int j = 0; j < 8; j++)
                tmp[j] = (__bf16)((float)(((qv >> (4*j)) & 15) - 8) * s2t[gs[j]*64 + c]);
            *reinterpret_cast<f32x4*>(&Bs[c * LDSK + kp * 8]) = *reinterpret_cast<f32x4*>(tmp);
        }
    }
    __syncthreads();

    const __bf16* bp = &Bs[lrow * LDSK + quad * 8];
    const int nmt = (mcount + 127) >> 7;
    for (int mt = 0; mt < nmt; mt++) {
        const __bf16* ap0 = act + (size_t)(mstart + mt*128 + wv*32 + lrow) * I_DIM + kz + quad*8;
        const __bf16* ap1 = ap0 + (size_t)16 * I_DIM;

        f32x4 acc[2][4];
        #pragma unroll
        for (int i = 0; i < 2; i++)
            #pragma unroll
            for (int j = 0; j < 4; j++) acc[i][j] = (f32x4)(0.f);

        auto loadT = [&](int kt, bf16x8& A0, bf16x8& A1, bf16x8* B) {
            A0 = *reinterpret_cast<const bf16x8*>(ap0 + kt*32);
            A1 = *reinterpret_cast<const bf16x8*>(ap1 + kt*32);
            #pragma unroll
            for (int j = 0; j < 4; j++)
                B[j] = *reinterpret_cast<const bf16x8*>(bp + j*16*LDSK + kt*32);
        };
        auto compT = [&](bf16x8 A0, bf16x8 A1, const bf16x8* B) {
            #pragma unroll
            for (int j = 0; j < 4; j++) {
                acc[0][j] = __builtin_amdgcn_mfma_f32_16x16x32_bf16(A0, B[j], acc[0][j], 0, 0, 0);
                acc[1][j] = __builtin_amdgcn_mfma_f32_16x16x32_bf16(A1, B[j], acc[1][j], 0, 0, 0);
            }
        };

        bf16x8 xa0, xa1, xb[4], ya0, ya1, yb[4];
        loadT(0, xa0, xa1, xb);
        #pragma unroll
        for (int kt = 0; kt < 32; kt += 2) {
            loadT(kt+1, ya0, ya1, yb);
            compT(xa0, xa1, xb);
            if (kt+2 < 32) loadT(kt+2, xa0, xa1, xb);
            compT(ya0, ya1, yb);
        }

        #pragma unroll
        for (int j = 0; j < 4; j++) {
            int h = n0 + 16*j + lrow;
            #pragma unroll
            for (int i = 0; i < 2; i++)
                #pragma unroll
                for (int rr = 0; rr < 4; rr++) {
                    int m = mt*128 + wv*32 + i*16 + quad*4 + rr;
                    if (m < mcount)
                        atomicAdd(&out[(size_t)toks[m] * H_DIM + h], acc[i][j][rr]);
                }
        }
    }
}

// =====================================================================
extern "C" void kernel_launch(void* const* d_in, const int* in_sizes, int n_in,
                              void* d_out, int out_size, void* d_ws, size_t ws_size,
                              hipStream_t stream) {
    const float* x      = (const float*)d_in[0];
    const float* logits = (const float*)d_in[1];
    const int*   w13q   = (const int*)  d_in[2];
    const int*   w2q    = (const int*)  d_in[3];
    const float* w13s   = (const float*)d_in[4];
    const float* w2s    = (const float*)d_in[5];
    const int*   g13    = (const int*)  d_in[6];
    const int*   g2     = (const int*)  d_in[7];

    char* ws = (char*)d_ws;
    int*    counts = (int*)   (ws + WS_COUNTS);
    int*    offs   = (int*)   (ws + WS_OFFS);
    int*    curs   = (int*)   (ws + WS_CURS);
    int*    tok_e  = (int*)   (ws + WS_TOKE);
    float*  tok_w  = (float*) (ws + WS_TOKW);
    int*    plist  = (int*)   (ws + WS_PLIST);
    float*  pw     = (float*) (ws + WS_PW);
    __bf16* xg     = (__bf16*)(ws + WS_XG);
    __bf16* act    = (__bf16*)(ws + WS_ACT);
    float*  out    = (float*) d_out;

    hipMemsetAsync(d_out, 0, (size_t)out_size * sizeof(float), stream);
    hipMemsetAsync(d_ws, 0, 256, stream);

    k_route  <<<T_TOK/256, 256, 0, stream>>>(logits, counts, tok_e, tok_w);
    k_scan   <<<1, 64, 0, stream>>>(counts, offs, curs);
    k_scatter<<<T_TOK/256, 256, 0, stream>>>(tok_e, tok_w, curs, plist, pw);
    k_gather <<<2*T_TOK, 128, 0, stream>>>(x, plist, xg);

    k_gemm1<<<NEXP * 128, 256, 0, stream>>>(xg, w13q, w13s, g13, offs, pw, act);
    k_gemm2<<<NEXP * KSPLIT2 * 16, 256, 0, stream>>>(act, w2q, w2s, g2, offs, plist, out);
}